// Round 2
// 662.757 us; speedup vs baseline: 1.4056x; 1.4056x over previous
//
#include <hip/hip_runtime.h>

#define T_STEPS 512

typedef __attribute__((ext_vector_type(8))) short s16x8;  // 8 bf16 (4 VGPRs)
typedef __attribute__((ext_vector_type(4))) float f32x4;  // MFMA C/D

__device__ __forceinline__ short f2bf(float v) {          // fp32 -> bf16 RNE
    unsigned u = __float_as_uint(v);
    return (short)((u + 0x7FFFu + ((u >> 16) & 1u)) >> 16);
}
__device__ __forceinline__ float bf2f(short b) {
    return __uint_as_float(((unsigned)(unsigned short)b) << 16);
}
__device__ __forceinline__ float sigf(float x)  { return 1.f / (1.f + __expf(-x)); }
__device__ __forceinline__ float tanhf_(float x){ float e = __expf(2.f * x); return 1.f - 2.f / (e + 1.f); }

// Each block: 4 batches, 1024 threads = 16 waves.
// Phase 1 (all 16 waves): wave w's MFMAs produce gates for states 4w..4w+3 of
//   BOTH layers; lanes n16<4 write the f32x4 gate vectors to an LDS gate
//   buffer indexed [state*4+batch].
// Phase 2 (after 2nd barrier): waves 0..3 compute ALL 256 L0 cells FULL-LANE
//   (lane -> state 16*w + (lane>>2), batch lane&3); waves 4..7 the 256 L1
//   cells; waves 8..11 stage x. This halves the issue count of the
//   transcendental-heavy cell section (16 masked wave-passes -> 8 dense).
__global__ __launch_bounds__(1024, 4)
void lstm2_mfma(const float* __restrict__ x,
                const float* __restrict__ Wih0, const float* __restrict__ Whh0,
                const float* __restrict__ bih0, const float* __restrict__ bhh0,
                const float* __restrict__ Wih1, const float* __restrict__ Whh1,
                const float* __restrict__ bih1, const float* __restrict__ bhh1,
                const float* __restrict__ Wfc,  const float* __restrict__ bfc,
                float* __restrict__ out)
{
    // B-operand buffers, bf16, [parity][n(16)][k]. Strides 104/136 shorts ->
    // b128 quad index (13n+..)/(17n+..) mod 32: 2-way worst case (free).
    __shared__ __align__(16) short vinB[2][16][104];  // k: 0..31 x_t, 32..95 h0
    __shared__ __align__(16) short u1B [2][16][136];  // k: 0..63 h0, 64..127 h1
    // gate buffers: [state*4 + batch] -> f32x4 (i,f,g,o). b128 write: 16 lanes,
    // 2 lanes/bank-quad (free). b128 read: 64 lanes, 8 lanes/quad = structural
    // minimum for wave64 b128 -> conflict-free beyond the floor.
    __shared__ __align__(16) float gbuf0[256 * 4];    // L0 gates
    __shared__ __align__(16) float gbuf1[256 * 4];    // L1 gates

    const int tid  = threadIdx.x;
    const int w    = tid >> 6;       // wave 0..15
    const int lane = tid & 63;
    const int n16  = lane & 15;      // MFMA col (batch for n<4) / A-row m
    const int q4   = lane >> 4;      // quad: D-state-slot; A k-run
    const int b0   = blockIdx.x * 4;

    // ---- A fragments (weights, bf16, loop-invariant). A[m=lane&15][k=q4*8+j].
    //      tile row m -> gate m&3, local state m>>2 -> global row: ----
    const int rowW = (n16 & 3) * 64 + 4 * w + (n16 >> 2);
    s16x8 a0, a1, a2;        // L0: K=96  = 3 tiles {x, h0_lo, h0_hi}
    s16x8 e0, e1, e2, e3;    // L1: K=128 = 4 tiles {h0 x2, h1 x2}
#pragma unroll
    for (int j = 0; j < 8; ++j) {
        a0[j] = f2bf(Wih0[rowW * 32 + q4 * 8 + j]);
        a1[j] = f2bf(Whh0[rowW * 64 + q4 * 8 + j]);
        a2[j] = f2bf(Whh0[rowW * 64 + 32 + q4 * 8 + j]);
        e0[j] = f2bf(Wih1[rowW * 64 + q4 * 8 + j]);
        e1[j] = f2bf(Wih1[rowW * 64 + 32 + q4 * 8 + j]);
        e2[j] = f2bf(Whh1[rowW * 64 + q4 * 8 + j]);
        e3[j] = f2bf(Whh1[rowW * 64 + 32 + q4 * 8 + j]);
    }

    // ---- bias as the MFMA C seed: reg p = gate p of state jL, all cols ----
    const int jL = 4 * w + q4;       // global state whose gates this lane's D holds
    f32x4 bias0, bias1;
#pragma unroll
    for (int p_ = 0; p_ < 4; ++p_) {
        bias0[p_] = bih0[p_ * 64 + jL] + bhh0[p_ * 64 + jL];
        bias1[p_] = bih1[p_ * 64 + jL] + bhh1[p_ * 64 + jL];
    }

    // ---- gate-buffer indices ----
    const int gwi = jL * 4 + n16;            // writer (phase 1, lanes n16<4)
    const int cw  = w & 3;                   // cell sub-wave id (waves 0..7)
    const int cs  = 16 * cw + (lane >> 2);   // cell state 0..63
    const int cb  = lane & 3;                // cell batch 0..3
    const int gri = 64 * cw + lane;          // == cs*4 + cb

    // ---- x stagers: waves 8..11 (idle in cell phase). Wave 8+b stages batch
    //      b's 32 x values with lanes 4<=n16<12. ----
    const bool isx = (w >= 8) && (w < 12) && (n16 >= 4) && (n16 < 12);
    const int  xb  = (w - 8) & 3;                        // staged batch
    const int  xk  = q4 * 8 + ((n16 - 4) & 7);           // 0..31
    const float* xp = x + ((size_t)(b0 + xb) * T_STEPS) * 32 + xk;

    // ---- init: zero both B-buffers (n>=4 cols stay zero forever); stage x_0 ----
    for (int i = tid; i < 2 * 16 * 104 / 2; i += 1024) ((int*)vinB)[i] = 0;
    for (int i = tid; i < 2 * 16 * 136 / 2; i += 1024) ((int*)u1B)[i]  = 0;
    __syncthreads();
    if (isx) vinB[0][xb][xk] = f2bf(xp[0]);
    __syncthreads();

    float cst0 = 0.f, cst1 = 0.f;    // fp32 cell states (live in cell-wave lanes)

    for (int it = 0; it <= T_STEPS; ++it) {
        const int p = it & 1;

        float xpre = 0.f;
        const bool havex = isx && (it + 1 < T_STEPS);
        if (havex) xpre = xp[(size_t)(it + 1) * 32];

        // ======== phase 1: gates via MFMA (all 16 waves) ========
        const short* vb = &vinB[p][n16][q4 * 8];
        s16x8 vb0 = *(const s16x8*)(vb);
        s16x8 vb1 = *(const s16x8*)(vb + 32);
        s16x8 vb2 = *(const s16x8*)(vb + 64);
        const short* ub = &u1B[p][n16][q4 * 8];
        s16x8 ub0 = *(const s16x8*)(ub);
        s16x8 ub1 = *(const s16x8*)(ub + 32);
        s16x8 ub2 = *(const s16x8*)(ub + 64);
        s16x8 ub3 = *(const s16x8*)(ub + 96);

        f32x4 d0 = __builtin_amdgcn_mfma_f32_16x16x32_bf16(a0, vb0, bias0, 0, 0, 0);
        d0 = __builtin_amdgcn_mfma_f32_16x16x32_bf16(a1, vb1, d0, 0, 0, 0);
        d0 = __builtin_amdgcn_mfma_f32_16x16x32_bf16(a2, vb2, d0, 0, 0, 0);
        f32x4 d1 = __builtin_amdgcn_mfma_f32_16x16x32_bf16(e0, ub0, bias1, 0, 0, 0);
        d1 = __builtin_amdgcn_mfma_f32_16x16x32_bf16(e1, ub1, d1, 0, 0, 0);
        d1 = __builtin_amdgcn_mfma_f32_16x16x32_bf16(e2, ub2, d1, 0, 0, 0);
        d1 = __builtin_amdgcn_mfma_f32_16x16x32_bf16(e3, ub3, d1, 0, 0, 0);

        if (n16 < 4) {               // publish gate vectors for (state jL, batch n16)
            *(f32x4*)&gbuf0[gwi * 4] = d0;
            *(f32x4*)&gbuf1[gwi * 4] = d1;
        }
        __syncthreads();             // gates visible

        // ======== phase 2: dense cells (waves 0..7) + x stage (8..11) ========
        if (w < 4) {
            if (it < T_STEPS) {      // L0 at step `it`: 256 cells, full-lane
                f32x4 g = *(const f32x4*)&gbuf0[gri * 4];
                float cc = sigf(g[1]) * cst0 + sigf(g[0]) * tanhf_(g[2]);
                cst0 = cc;
                short hb = f2bf(sigf(g[3]) * tanhf_(cc));
                vinB[p ^ 1][cb][32 + cs] = hb;   // L0's next input
                u1B [p ^ 1][cb][cs]      = hb;   // L1's input (k = cs)
            }
        } else if (w < 8) {
            if (it >= 1) {           // L1 at step `it-1`: 256 cells, full-lane
                f32x4 g = *(const f32x4*)&gbuf1[gri * 4];
                float cc = sigf(g[1]) * cst1 + sigf(g[0]) * tanhf_(g[2]);
                cst1 = cc;
                u1B[p ^ 1][cb][64 + cs] = f2bf(sigf(g[3]) * tanhf_(cc));
            }
        }
        if (havex) vinB[p ^ 1][xb][xk] = f2bf(xpre);
        __syncthreads();             // h + x visible for next step
    }

    // ---- final FC on h1[T-1] (last L1 write: it=512, p=0 -> u1B[1]) ----
    if (tid < 4) {
        float s = bfc[0];
#pragma unroll
        for (int k = 0; k < 64; ++k)
            s += bf2f(u1B[1][tid][64 + k]) * Wfc[k];
        out[b0 + tid] = s;
    }
}

extern "C" void kernel_launch(void* const* d_in, const int* in_sizes, int n_in,
                              void* d_out, int out_size, void* d_ws, size_t ws_size,
                              hipStream_t stream) {
    const float* x    = (const float*)d_in[0];
    const float* Wih0 = (const float*)d_in[1];
    const float* Whh0 = (const float*)d_in[2];
    const float* bih0 = (const float*)d_in[3];
    const float* bhh0 = (const float*)d_in[4];
    const float* Wih1 = (const float*)d_in[5];
    const float* Whh1 = (const float*)d_in[6];
    const float* bih1 = (const float*)d_in[7];
    const float* bhh1 = (const float*)d_in[8];
    const float* Wfc  = (const float*)d_in[9];
    const float* bfc  = (const float*)d_in[10];
    float* out = (float*)d_out;

    const int B = out_size;            // 1024
    dim3 grid(B / 4), block(1024);
    hipLaunchKernelGGL(lstm2_mfma, grid, block, 0, stream,
                       x, Wih0, Whh0, bih0, bhh0,
                       Wih1, Whh1, bih1, bhh1, Wfc, bfc, out);
}

// Round 3
// 584.597 us; speedup vs baseline: 1.5936x; 1.1337x over previous
//
#include <hip/hip_runtime.h>

#define T_STEPS 512

typedef __attribute__((ext_vector_type(8))) short s16x8;  // 8 bf16 (4 VGPRs)
typedef __attribute__((ext_vector_type(4))) float f32x4;  // MFMA C/D

__device__ __forceinline__ short f2bf(float v) {          // fp32 -> bf16 RNE
    unsigned u = __float_as_uint(v);
    return (short)((u + 0x7FFFu + ((u >> 16) & 1u)) >> 16);
}
__device__ __forceinline__ float bf2f(short b) {
    return __uint_as_float(((unsigned)(unsigned short)b) << 16);
}
__device__ __forceinline__ float sigf(float x)  { return 1.f / (1.f + __expf(-x)); }
__device__ __forceinline__ float tanhf_(float x){ float e = __expf(2.f * x); return 1.f - 2.f / (e + 1.f); }

// Each block: 4 batches, 1024 threads = 16 waves.
// Phase 1 (all 16 waves): wave w's MFMAs produce gates for states 4w..4w+3 of
//   BOTH layers; lanes n16<4 write the f32x4 gate vectors to an LDS gate
//   buffer indexed [state*4+batch].
// Phase 2 (after 2nd barrier): waves 0..3 compute ALL 256 L0 cells FULL-LANE;
//   waves 4..7 the 256 L1 cells; waves 8..11 stage x.
// B-read trick: only MFMA columns 0..3 are real batches. B-column n is sourced
//   only from lanes lane&15==n, and garbage in cols 4..15 corrupts only D-cols
//   4..15 (never read). Lanes n16>=4 read column 3's address -> same-address
//   LDS broadcast (no bank cost) -> ~4x less LDS bank traffic on the critical
//   path, zero divergence, bit-identical math.
__global__ __launch_bounds__(1024, 4)
void lstm2_mfma(const float* __restrict__ x,
                const float* __restrict__ Wih0, const float* __restrict__ Whh0,
                const float* __restrict__ bih0, const float* __restrict__ bhh0,
                const float* __restrict__ Wih1, const float* __restrict__ Whh1,
                const float* __restrict__ bih1, const float* __restrict__ bhh1,
                const float* __restrict__ Wfc,  const float* __restrict__ bfc,
                float* __restrict__ out)
{
    // B-operand buffers, bf16, [parity][n(16)][k].
    __shared__ __align__(16) short vinB[2][16][104];  // k: 0..31 x_t, 32..95 h0
    __shared__ __align__(16) short u1B [2][16][136];  // k: 0..63 h0, 64..127 h1
    // gate buffers: [state*4 + batch] -> f32x4 (i,f,g,o).
    __shared__ __align__(16) float gbuf0[256 * 4];    // L0 gates
    __shared__ __align__(16) float gbuf1[256 * 4];    // L1 gates

    const int tid  = threadIdx.x;
    const int w    = tid >> 6;       // wave 0..15
    const int lane = tid & 63;
    const int n16  = lane & 15;      // MFMA col (batch for n<4) / A-row m
    const int q4   = lane >> 4;      // quad: D-state-slot; A k-run
    const int b0   = blockIdx.x * 4;

    // ---- A fragments (weights, bf16, loop-invariant). A[m=lane&15][k=q4*8+j].
    const int rowW = (n16 & 3) * 64 + 4 * w + (n16 >> 2);
    s16x8 a0, a1, a2;        // L0: K=96  = 3 tiles {x, h0_lo, h0_hi}
    s16x8 e0, e1, e2, e3;    // L1: K=128 = 4 tiles {h0 x2, h1 x2}
#pragma unroll
    for (int j = 0; j < 8; ++j) {
        a0[j] = f2bf(Wih0[rowW * 32 + q4 * 8 + j]);
        a1[j] = f2bf(Whh0[rowW * 64 + q4 * 8 + j]);
        a2[j] = f2bf(Whh0[rowW * 64 + 32 + q4 * 8 + j]);
        e0[j] = f2bf(Wih1[rowW * 64 + q4 * 8 + j]);
        e1[j] = f2bf(Wih1[rowW * 64 + 32 + q4 * 8 + j]);
        e2[j] = f2bf(Whh1[rowW * 64 + q4 * 8 + j]);
        e3[j] = f2bf(Whh1[rowW * 64 + 32 + q4 * 8 + j]);
    }

    // ---- bias as the MFMA C seed: reg p = gate p of state jL, all cols ----
    const int jL = 4 * w + q4;       // global state whose gates this lane's D holds
    f32x4 bias0, bias1;
#pragma unroll
    for (int p_ = 0; p_ < 4; ++p_) {
        bias0[p_] = bih0[p_ * 64 + jL] + bhh0[p_ * 64 + jL];
        bias1[p_] = bih1[p_ * 64 + jL] + bhh1[p_ * 64 + jL];
    }

    // ---- gate-buffer indices ----
    const int gwi = jL * 4 + n16;            // writer (phase 1, lanes n16<4)
    const int cw  = w & 3;                   // cell sub-wave id (waves 0..7)
    const int cs  = 16 * cw + (lane >> 2);   // cell state 0..63
    const int cb  = lane & 3;                // cell batch 0..3
    const int gri = 64 * cw + lane;          // == cs*4 + cb

    // ---- B-read column: clamp to 3 for the 48 phantom-column lanes ----
    const int nB  = (n16 < 4) ? n16 : 3;     // same-addr broadcast for n16>=4

    // ---- x stagers: waves 8..11 (idle in cell phase). Wave 8+b stages batch
    //      b's 32 x values with lanes 4<=n16<12. ----
    const bool isx = (w >= 8) && (w < 12) && (n16 >= 4) && (n16 < 12);
    const int  xb  = (w - 8) & 3;                        // staged batch
    const int  xk  = q4 * 8 + ((n16 - 4) & 7);           // 0..31
    const float* xp = x + ((size_t)(b0 + xb) * T_STEPS) * 32 + xk;

    // ---- init: zero both B-buffers; stage x_0 ----
    for (int i = tid; i < 2 * 16 * 104 / 2; i += 1024) ((int*)vinB)[i] = 0;
    for (int i = tid; i < 2 * 16 * 136 / 2; i += 1024) ((int*)u1B)[i]  = 0;
    __syncthreads();
    if (isx) vinB[0][xb][xk] = f2bf(xp[0]);
    __syncthreads();

    float cst0 = 0.f, cst1 = 0.f;    // fp32 cell states (live in cell-wave lanes)

    for (int it = 0; it <= T_STEPS; ++it) {
        const int p = it & 1;

        float xpre = 0.f;
        const bool havex = isx && (it + 1 < T_STEPS);
        if (havex) xpre = xp[(size_t)(it + 1) * 32];

        // ======== phase 1: gates via MFMA (all 16 waves) ========
        const short* vb = &vinB[p][nB][q4 * 8];
        s16x8 vb0 = *(const s16x8*)(vb);
        s16x8 vb1 = *(const s16x8*)(vb + 32);
        s16x8 vb2 = *(const s16x8*)(vb + 64);
        const short* ub = &u1B[p][nB][q4 * 8];
        s16x8 ub0 = *(const s16x8*)(ub);
        s16x8 ub1 = *(const s16x8*)(ub + 32);
        s16x8 ub2 = *(const s16x8*)(ub + 64);
        s16x8 ub3 = *(const s16x8*)(ub + 96);

        f32x4 d0 = __builtin_amdgcn_mfma_f32_16x16x32_bf16(a0, vb0, bias0, 0, 0, 0);
        d0 = __builtin_amdgcn_mfma_f32_16x16x32_bf16(a1, vb1, d0, 0, 0, 0);
        d0 = __builtin_amdgcn_mfma_f32_16x16x32_bf16(a2, vb2, d0, 0, 0, 0);
        f32x4 d1 = __builtin_amdgcn_mfma_f32_16x16x32_bf16(e0, ub0, bias1, 0, 0, 0);
        d1 = __builtin_amdgcn_mfma_f32_16x16x32_bf16(e1, ub1, d1, 0, 0, 0);
        d1 = __builtin_amdgcn_mfma_f32_16x16x32_bf16(e2, ub2, d1, 0, 0, 0);
        d1 = __builtin_amdgcn_mfma_f32_16x16x32_bf16(e3, ub3, d1, 0, 0, 0);

        if (n16 < 4) {               // publish gate vectors for (state jL, batch n16)
            *(f32x4*)&gbuf0[gwi * 4] = d0;
            *(f32x4*)&gbuf1[gwi * 4] = d1;
        }
        __syncthreads();             // gates visible

        // ======== phase 2: dense cells (waves 0..7) + x stage (8..11) ========
        if (w < 4) {
            if (it < T_STEPS) {      // L0 at step `it`: 256 cells, full-lane
                f32x4 g = *(const f32x4*)&gbuf0[gri * 4];
                float cc = sigf(g[1]) * cst0 + sigf(g[0]) * tanhf_(g[2]);
                cst0 = cc;
                short hb = f2bf(sigf(g[3]) * tanhf_(cc));
                vinB[p ^ 1][cb][32 + cs] = hb;   // L0's next input
                u1B [p ^ 1][cb][cs]      = hb;   // L1's input (k = cs)
            }
        } else if (w < 8) {
            if (it >= 1) {           // L1 at step `it-1`: 256 cells, full-lane
                f32x4 g = *(const f32x4*)&gbuf1[gri * 4];
                float cc = sigf(g[1]) * cst1 + sigf(g[0]) * tanhf_(g[2]);
                cst1 = cc;
                u1B[p ^ 1][cb][64 + cs] = f2bf(sigf(g[3]) * tanhf_(cc));
            }
        }
        if (havex) vinB[p ^ 1][xb][xk] = f2bf(xpre);
        __syncthreads();             // h + x visible for next step
    }

    // ---- final FC on h1[T-1] (last L1 write: it=512, p=0 -> u1B[1]) ----
    if (tid < 4) {
        float s = bfc[0];
#pragma unroll
        for (int k = 0; k < 64; ++k)
            s += bf2f(u1B[1][tid][64 + k]) * Wfc[k];
        out[b0 + tid] = s;
    }
}

extern "C" void kernel_launch(void* const* d_in, const int* in_sizes, int n_in,
                              void* d_out, int out_size, void* d_ws, size_t ws_size,
                              hipStream_t stream) {
    const float* x    = (const float*)d_in[0];
    const float* Wih0 = (const float*)d_in[1];
    const float* Whh0 = (const float*)d_in[2];
    const float* bih0 = (const float*)d_in[3];
    const float* bhh0 = (const float*)d_in[4];
    const float* Wih1 = (const float*)d_in[5];
    const float* Whh1 = (const float*)d_in[6];
    const float* bih1 = (const float*)d_in[7];
    const float* bhh1 = (const float*)d_in[8];
    const float* Wfc  = (const float*)d_in[9];
    const float* bfc  = (const float*)d_in[10];
    float* out = (float*)d_out;

    const int B = out_size;            // 1024
    dim3 grid(B / 4), block(1024);
    hipLaunchKernelGGL(lstm2_mfma, grid, block, 0, stream,
                       x, Wih0, Whh0, bih0, bhh0,
                       Wih1, Whh1, bih1, bhh1, Wfc, bfc, out);
}